// Round 23
// baseline (62.320 us; speedup 1.0000x reference)
//
#include <hip/hip_runtime.h>

#define NN 50
#define D 64
#define GRP 10

typedef unsigned int uint32;
typedef unsigned short ushort16;

__device__ __forceinline__ float wave_sum64(float x) {
#pragma unroll
  for (int off = 32; off > 0; off >>= 1)
    x += __shfl_xor(x, off, 64);
  return x;
}

__device__ __forceinline__ float readlane_f(float v, int l) {
  return __uint_as_float(__builtin_amdgcn_readlane(__float_as_uint(v), l));
}

__device__ __forceinline__ ushort16 f32_to_bf16(float f) {
  uint32 u = __float_as_uint(f);
  u += 0x7FFF + ((u >> 16) & 1);          // round-to-nearest-even
  return (ushort16)(u >> 16);
}

// ==== PREP: blocks [0,pblocks) = ent_proj; blocks [pblocks,+16) = W2@cW fuse =
__global__ __launch_bounds__(256, 4) void kgat_prep(
    const float* __restrict__ ent_tab, const float* __restrict__ attn_W,
    float* __restrict__ proj, ushort16* __restrict__ ent_bf, int rows,
    int pblocks,
    const float* __restrict__ W2, const float* __restrict__ b2,
    const float* __restrict__ cW, const float* __restrict__ cb,
    float* __restrict__ W2cW, float* __restrict__ cb2)
{
  const int lane = threadIdx.x & 63;
  const int wv   = threadIdx.x >> 6;

  if ((int)blockIdx.x < pblocks) {
    const long wave = (long)blockIdx.x * 4 + wv;
    const long base = wave * GRP;
    if (base >= rows) return;
    const float Wn = attn_W[D + lane];
    float v[GRP];
#pragma unroll
    for (int i = 0; i < GRP; ++i) {
      long r = base + i; if (r > rows - 1) r = rows - 1;
      v[i] = ent_tab[r * D + lane];         // coalesced, contiguous rows
    }
    float s[GRP];
#pragma unroll
    for (int i = 0; i < GRP; ++i)
      s[i] = wave_sum64(v[i] * Wn);         // 10 independent butterfly chains
#pragma unroll
    for (int i = 0; i < GRP; ++i) {
      const long r = base + i;
      if (r < rows) ent_bf[r * D + lane] = f32_to_bf16(v[i]);
    }
    if (lane == 0) {
#pragma unroll
      for (int i = 0; i < GRP; ++i)
        if (base + i < rows) proj[base + i] = s[i];
    }
  } else {
    // weight fusion: W2cW = W2 @ cW_bot; cb2 = cb + b2 @ cW_bot
    const int d = ((int)blockIdx.x - pblocks) * 4 + wv;   // 0..63
    float acc = 0.f;
#pragma unroll 8
    for (int k = 0; k < D; ++k)
      acc = fmaf(W2[d * D + k], cW[(D + k) * D + lane], acc);
    W2cW[d * D + lane] = acc;
    if (d == 0) {
      float a2 = 0.f;
#pragma unroll 8
      for (int k = 0; k < D; ++k)
        a2 = fmaf(b2[k], cW[(D + k) * D + lane], a2);
      cb2[lane] = cb[lane] + a2;
    }
  }
}

// ===== A: attention, paired-row gathers (R20-proven, 2 rows / wave-load) ====
#define PGRP 5

__device__ __forceinline__ void load_pair_grp(uint32 (&buf)[PGRP],
                                              const int* __restrict__ adjb,
                                              const uint32* __restrict__ ent32,
                                              int g, int half, int sub) {
#pragma unroll
  for (int i = 0; i < PGRP; ++i) {
    const int p = g * PGRP + i;
    int t0 = adjb[2 * p + 0]; t0 = t0 < 0 ? 0 : t0;
    int t1 = adjb[2 * p + 1]; t1 = t1 < 0 ? 0 : t1;
    const int t = half ? t1 : t0;
    buf[i] = ent32[(size_t)t * 32 + sub];   // 4B/lane, 2 rows per instruction
  }
}

__device__ __forceinline__ void acc_pair_grp(const uint32 (&buf)[PGRP],
                                             float e, int g, int half,
                                             float& lo0, float& lo1,
                                             float& hi0, float& hi1) {
#pragma unroll
  for (int i = 0; i < PGRP; ++i) {
    const int p = g * PGRP + i;
    const float w0 = readlane_f(e, 2 * p + 0);
    const float w1 = readlane_f(e, 2 * p + 1);
    const float w  = half ? w1 : w0;
    const float lo = __uint_as_float(buf[i] << 16);          // bf16 dim 2*sub
    const float hi = __uint_as_float(buf[i] & 0xFFFF0000u);  // bf16 dim 2*sub+1
    if (i & 1) { lo1 = fmaf(w, lo, lo1); hi1 = fmaf(w, hi, hi1); }
    else       { lo0 = fmaf(w, lo, lo0); hi0 = fmaf(w, hi, hi0); }
  }
}

__global__ __launch_bounds__(256, 4) void kgat_attn2(
    const int* __restrict__ item_idx, const int* __restrict__ adj,
    const float* __restrict__ item_tab,
    const uint32* __restrict__ ent32, const float* __restrict__ proj,
    const float* __restrict__ attn_W, const float* __restrict__ attn_b,
    float* __restrict__ naws, int B)
{
  const int lane = threadIdx.x & 63;
  const int wv   = threadIdx.x >> 6;
  const int b    = blockIdx.x * 4 + wv;
  if (b >= B) return;
  const int half = lane >> 5;
  const int sub  = lane & 31;

  const int* adjb = adj + (long)b * NN;

  uint32 GA[PGRP], GB[PGRP];
  load_pair_grp(GA, adjb, ent32, 0, half, sub);
  load_pair_grp(GB, adjb, ent32, 1, half, sub);

  const float item = item_tab[(long)item_idx[b] * D + lane];
  const float base = wave_sum64(item * attn_W[lane]) + attn_b[0];  // uniform

  const int myn = lane < NN ? lane : NN - 1;
  int mi = adjb[myn]; mi = mi < 0 ? 0 : mi;
  float s = proj[mi] + base;
  s = s > 0.f ? s : 0.2f * s;                     // leaky_relu(0.2)
  // scores are leaky_relu of ~unit-variance dots, bounded well below 8 ->
  // exp(s-8) can't overflow, denom can't underflow to 0.
  const float e = (lane < NN) ? __expf(s - 8.0f) : 0.f;
  const float denom = wave_sum64(e);

  float lo0 = 0.f, lo1 = 0.f, hi0 = 0.f, hi1 = 0.f;
  acc_pair_grp(GA, e, 0, half, lo0, lo1, hi0, hi1);
  load_pair_grp(GA, adjb, ent32, 2, half, sub);
  acc_pair_grp(GB, e, 1, half, lo0, lo1, hi0, hi1);
  load_pair_grp(GB, adjb, ent32, 3, half, sub);
  acc_pair_grp(GA, e, 2, half, lo0, lo1, hi0, hi1);
  load_pair_grp(GA, adjb, ent32, 4, half, sub);
  acc_pair_grp(GB, e, 3, half, lo0, lo1, hi0, hi1);
  acc_pair_grp(GA, e, 4, half, lo0, lo1, hi0, hi1);

  float nlo = lo0 + lo1;
  float nhi = hi0 + hi1;
  nlo += __shfl_xor(nlo, 32, 64);
  nhi += __shfl_xor(nhi, 32, 64);

  const float inv = 1.0f / denom;
  if (lane < 32) {                                 // coalesced float2 store
    float2 val = make_float2(nlo * inv, nhi * inv);
    *(float2*)(naws + (long)b * D + 2 * sub) = val;
  }
}

// ===== M: fused MLP, 2 elems/wave (grid 2048 -> 32 waves/CU occupancy) ======
// f = relu( item@cW_top + h@W2cW + cb2 ), h = relu(na@W1 + b1)
__global__ __launch_bounds__(256, 8) void kgat_mlpf2(
    const int* __restrict__ user_idx, const int* __restrict__ item_idx,
    const float* __restrict__ user_tab, const float* __restrict__ item_tab,
    const float* __restrict__ naws,
    const float* __restrict__ W1, const float* __restrict__ b1,
    const float* __restrict__ cW,
    const float* __restrict__ W2cW, const float* __restrict__ cb2,
    const float* __restrict__ oW, const float* __restrict__ ob,
    float* __restrict__ out, int B)
{
  __shared__ __align__(16) float s_h[4 * 2 * D];   // h broadcast (2 elem/wave)

  const int lane = threadIdx.x & 63;
  const int wv   = threadIdx.x >> 6;
  const int b0   = (blockIdx.x * 4 + wv) * 2;
  if (b0 >= B) return;

  float* shA = s_h + (wv * 2 + 0) * D;
  float* shB = s_h + (wv * 2 + 1) * D;

  const int bA = b0 + 0 < B ? b0 + 0 : B - 1;
  const int bB = b0 + 1 < B ? b0 + 1 : B - 1;

  // wave-uniform activation bases -> scalar-pipe loads
  const int uA = __builtin_amdgcn_readfirstlane(bA);
  const int uB = __builtin_amdgcn_readfirstlane(bB);
  const float* napA = naws + (long)uA * D;
  const float* napB = naws + (long)uB * D;
  const int iiA = __builtin_amdgcn_readfirstlane(item_idx[bA]);
  const int iiB = __builtin_amdgcn_readfirstlane(item_idx[bB]);
  const float* itpA = item_tab + (long)iiA * D;
  const float* itpB = item_tab + (long)iiB * D;

  // user rows per-lane (lane = dim), coalesced
  const float usA = user_tab[(long)user_idx[bA] * D + lane];
  const float usB = user_tab[(long)user_idx[bB] * D + lane];

  // ---- phase A (merged): h-acc = na@W1 + b1  AND  f-acc = item@cW + cb2 ----
  const float b1v  = b1[lane];
  const float cb2v = cb2[lane];
  float hA0 = b1v, hA1 = 0.f, hB0 = b1v, hB1 = 0.f;
  float fA0 = cb2v, fA1 = 0.f, fB0 = cb2v, fB1 = 0.f;
#pragma unroll
  for (int d = 0; d < D; d += 4) {
    const float v0 = W1[(d + 0) * D + lane];
    const float v1 = W1[(d + 1) * D + lane];
    const float v2 = W1[(d + 2) * D + lane];
    const float v3 = W1[(d + 3) * D + lane];
    const float w0 = cW[(d + 0) * D + lane];
    const float w1 = cW[(d + 1) * D + lane];
    const float w2 = cW[(d + 2) * D + lane];
    const float w3 = cW[(d + 3) * D + lane];
    const float4 aA = *(const float4*)(napA + d);
    const float4 aB = *(const float4*)(napB + d);
    const float4 iA = *(const float4*)(itpA + d);
    const float4 iB = *(const float4*)(itpB + d);
    hA0 = fmaf(aA.x, v0, hA0); hA1 = fmaf(aA.y, v1, hA1);
    hA0 = fmaf(aA.z, v2, hA0); hA1 = fmaf(aA.w, v3, hA1);
    hB0 = fmaf(aB.x, v0, hB0); hB1 = fmaf(aB.y, v1, hB1);
    hB0 = fmaf(aB.z, v2, hB0); hB1 = fmaf(aB.w, v3, hB1);
    fA0 = fmaf(iA.x, w0, fA0); fA1 = fmaf(iA.y, w1, fA1);
    fA0 = fmaf(iA.z, w2, fA0); fA1 = fmaf(iA.w, w3, fA1);
    fB0 = fmaf(iB.x, w0, fB0); fB1 = fmaf(iB.y, w1, fB1);
    fB0 = fmaf(iB.z, w2, fB0); fB1 = fmaf(iB.w, w3, fB1);
  }
  shA[lane] = fmaxf(hA0 + hA1, 0.f);               // wave-private, no barrier
  shB[lane] = fmaxf(hB0 + hB1, 0.f);

  // ---- phase B: f += h @ W2cW (h via LDS broadcast) ----
#pragma unroll
  for (int d = 0; d < D; d += 4) {
    const float w0 = W2cW[(d + 0) * D + lane];
    const float w1 = W2cW[(d + 1) * D + lane];
    const float w2 = W2cW[(d + 2) * D + lane];
    const float w3 = W2cW[(d + 3) * D + lane];
    const float4 cA = *(const float4*)(shA + d);
    const float4 cB = *(const float4*)(shB + d);
    fA0 = fmaf(cA.x, w0, fA0); fA1 = fmaf(cA.y, w1, fA1);
    fA0 = fmaf(cA.z, w2, fA0); fA1 = fmaf(cA.w, w3, fA1);
    fB0 = fmaf(cB.x, w0, fB0); fB1 = fmaf(cB.y, w1, fB1);
    fB0 = fmaf(cB.z, w2, fB0); fB1 = fmaf(cB.w, w3, fB1);
  }
  const float fA = fmaxf(fA0 + fA1, 0.f);
  const float fB = fmaxf(fB0 + fB1, 0.f);

  // ---- score = dot([user, f], oW) + ob ----
  const float oWu = oW[lane];
  const float oWf = oW[D + lane];
  const float ob0 = ob[0];
  const float scA = wave_sum64(fmaf(usA, oWu, fA * oWf));
  const float scB = wave_sum64(fmaf(usB, oWu, fB * oWf));
  if (lane == 0) {
    out[bA] = scA + ob0;
    if (bB != bA) out[bB] = scB + ob0;
  }
}

// ================= fallback: exact R3 kernel (small/no workspace) ===========
__device__ __forceinline__ void load_grp(float (&buf)[GRP],
                                         const int* __restrict__ adjb,
                                         const float* __restrict__ ent_tab,
                                         int g, int lane) {
#pragma unroll
  for (int i = 0; i < GRP; ++i) {
    int t = adjb[g * GRP + i];
    t = t < 0 ? 0 : t;
    buf[i] = ent_tab[(long)t * D + lane];
  }
}

__device__ __forceinline__ void proc_grp(const float (&buf)[GRP],
                                         float Wn, float base,
                                         float& l0, float& l1, float& na) {
  float ex[GRP];
#pragma unroll
  for (int i = 0; i < GRP; ++i) {
    float t = wave_sum64(buf[i] * Wn) + base;
    t = t > 0.f ? t : 0.2f * t;
    ex[i] = __expf(t - 8.0f);
  }
#pragma unroll
  for (int i = 0; i < GRP; ++i) {
    if (i & 1) l1 += ex[i]; else l0 += ex[i];
    na = fmaf(ex[i], buf[i], na);
  }
}

__global__ __launch_bounds__(256, 4) void kgat_r3(
    const int* __restrict__ user_idx, const int* __restrict__ item_idx,
    const int* __restrict__ adj,
    const float* __restrict__ user_tab, const float* __restrict__ item_tab,
    const float* __restrict__ ent_tab,
    const float* __restrict__ attn_W, const float* __restrict__ attn_b,
    const float* __restrict__ W1, const float* __restrict__ b1,
    const float* __restrict__ W2, const float* __restrict__ b2,
    const float* __restrict__ cW, const float* __restrict__ cb,
    const float* __restrict__ oW, const float* __restrict__ ob,
    float* __restrict__ out, int B)
{
  const int lane = threadIdx.x & 63;
  const int wv   = threadIdx.x >> 6;
  const int b    = blockIdx.x * 4 + wv;
  if (b >= B) return;

  const float user = user_tab[(long)user_idx[b] * D + lane];
  const float oWu  = oW[lane];
  const float oWf  = oW[D + lane];
  const float item = item_tab[(long)item_idx[b] * D + lane];
  const float Wi   = attn_W[lane];
  const float Wn   = attn_W[D + lane];
  const float base = wave_sum64(item * Wi) + attn_b[0];
  const int* adjb = adj + b * NN;

  float na = 0.f, l0 = 0.f, l1 = 0.f;
  float A[GRP], Bv[GRP];
  load_grp(A,  adjb, ent_tab, 0, lane);
  load_grp(Bv, adjb, ent_tab, 1, lane);
  proc_grp(A,  Wn, base, l0, l1, na);
  load_grp(A,  adjb, ent_tab, 2, lane);
  proc_grp(Bv, Wn, base, l0, l1, na);
  load_grp(Bv, adjb, ent_tab, 3, lane);
  proc_grp(A,  Wn, base, l0, l1, na);
  load_grp(A,  adjb, ent_tab, 4, lane);
  proc_grp(Bv, Wn, base, l0, l1, na);
  proc_grp(A,  Wn, base, l0, l1, na);
  na /= (l0 + l1);

  float h0 = b1[lane], h1 = 0.f, h2 = 0.f, h3 = 0.f;
#pragma unroll
  for (int d = 0; d < D; d += 4) {
    h0 = fmaf(readlane_f(na, d + 0), W1[(d + 0) * D + lane], h0);
    h1 = fmaf(readlane_f(na, d + 1), W1[(d + 1) * D + lane], h1);
    h2 = fmaf(readlane_f(na, d + 2), W1[(d + 2) * D + lane], h2);
    h3 = fmaf(readlane_f(na, d + 3), W1[(d + 3) * D + lane], h3);
  }
  const float h = fmaxf((h0 + h1) + (h2 + h3), 0.f);

  float r0 = b2[lane], r1 = 0.f, r2 = 0.f, r3 = 0.f;
#pragma unroll
  for (int d = 0; d < D; d += 4) {
    r0 = fmaf(readlane_f(h, d + 0), W2[(d + 0) * D + lane], r0);
    r1 = fmaf(readlane_f(h, d + 1), W2[(d + 1) * D + lane], r1);
    r2 = fmaf(readlane_f(h, d + 2), W2[(d + 2) * D + lane], r2);
    r3 = fmaf(readlane_f(h, d + 3), W2[(d + 3) * D + lane], r3);
  }
  const float r = (r0 + r1) + (r2 + r3);

  float f0 = cb[lane], f1 = 0.f, f2 = 0.f, f3 = 0.f;
#pragma unroll
  for (int k = 0; k < D; k += 4) {
    f0 = fmaf(readlane_f(item, k + 0), cW[(k + 0) * D + lane], f0);
    f1 = fmaf(readlane_f(item, k + 1), cW[(k + 1) * D + lane], f1);
    f2 = fmaf(readlane_f(item, k + 2), cW[(k + 2) * D + lane], f2);
    f3 = fmaf(readlane_f(item, k + 3), cW[(k + 3) * D + lane], f3);
  }
#pragma unroll
  for (int k = 0; k < D; k += 4) {
    f0 = fmaf(readlane_f(r, k + 0), cW[(D + k + 0) * D + lane], f0);
    f1 = fmaf(readlane_f(r, k + 1), cW[(D + k + 1) * D + lane], f1);
    f2 = fmaf(readlane_f(r, k + 2), cW[(D + k + 2) * D + lane], f2);
    f3 = fmaf(readlane_f(r, k + 3), cW[(D + k + 3) * D + lane], f3);
  }
  const float f = fmaxf((f0 + f1) + (f2 + f3), 0.f);

  const float sc = wave_sum64(fmaf(user, oWu, f * oWf));
  if (lane == 0) out[b] = sc + ob[0];
}

extern "C" void kernel_launch(void* const* d_in, const int* in_sizes, int n_in,
                              void* d_out, int out_size, void* d_ws, size_t ws_size,
                              hipStream_t stream) {
  const int*   user_idx = (const int*)d_in[0];
  const int*   item_idx = (const int*)d_in[1];
  const int*   adj      = (const int*)d_in[2];
  const float* user_tab = (const float*)d_in[3];
  const float* item_tab = (const float*)d_in[4];
  const float* ent_tab  = (const float*)d_in[5];
  const float* attn_W   = (const float*)d_in[6];
  const float* attn_b   = (const float*)d_in[7];
  const float* W1       = (const float*)d_in[8];
  const float* b1       = (const float*)d_in[9];
  const float* W2       = (const float*)d_in[10];
  const float* b2       = (const float*)d_in[11];
  const float* cW       = (const float*)d_in[12];
  const float* cb       = (const float*)d_in[13];
  const float* oW       = (const float*)d_in[14];
  const float* ob       = (const float*)d_in[15];
  float* out = (float*)d_out;

  const int B    = in_sizes[0];
  const int rows = in_sizes[5] / D;               // entity count

  // ws layout: [proj f32][ent_bf bf16][naws f32][W2cW f32][cb2 f32]
  const size_t off_bf = ((size_t)rows * 4 + 255) & ~(size_t)255;
  const size_t off_na = (off_bf + (size_t)rows * D * 2 + 255) & ~(size_t)255;
  const size_t off_w2 = (off_na + (size_t)B * D * 4 + 255) & ~(size_t)255;
  const size_t off_cb = off_w2 + (size_t)D * D * 4;
  const size_t need   = off_cb + (size_t)D * 4;

  if (ws_size >= need) {
    float*    proj   = (float*)d_ws;
    ushort16* ent_bf = (ushort16*)((char*)d_ws + off_bf);
    float*    naws   = (float*)((char*)d_ws + off_na);
    float*    W2cW   = (float*)((char*)d_ws + off_w2);
    float*    cb2    = (float*)((char*)d_ws + off_cb);
    const int waves   = (rows + GRP - 1) / GRP;
    const int pblocks = (waves + 3) / 4;
    const int ablocks = (B + 3) / 4;              // attention: 1 elem/wave
    const int mblocks = (B + 7) / 8;              // MLP: 2 elems/wave
    kgat_prep<<<pblocks + 16, 256, 0, stream>>>(ent_tab, attn_W, proj, ent_bf,
                                                rows, pblocks, W2, b2, cW, cb,
                                                W2cW, cb2);
    kgat_attn2<<<ablocks, 256, 0, stream>>>(item_idx, adj, item_tab,
                                            (const uint32*)ent_bf, proj,
                                            attn_W, attn_b, naws, B);
    kgat_mlpf2<<<mblocks, 256, 0, stream>>>(user_idx, item_idx, user_tab,
                                            item_tab, naws, W1, b1, cW,
                                            W2cW, cb2, oW, ob, out, B);
  } else {
    const int blocks = (B + 3) / 4;
    kgat_r3<<<blocks, 256, 0, stream>>>(user_idx, item_idx, adj,
                                        user_tab, item_tab, ent_tab,
                                        attn_W, attn_b, W1, b1, W2, b2,
                                        cW, cb, oW, ob, out, B);
  }
}

// Round 24
// 56.851 us; speedup vs baseline: 1.0962x; 1.0962x over previous
//
#include <hip/hip_runtime.h>

#define NN 50
#define D 64
#define GRP 10

typedef unsigned int uint32;
typedef unsigned short ushort16;

__device__ __forceinline__ float wave_sum64(float x) {
#pragma unroll
  for (int off = 32; off > 0; off >>= 1)
    x += __shfl_xor(x, off, 64);
  return x;
}

__device__ __forceinline__ float readlane_f(float v, int l) {
  return __uint_as_float(__builtin_amdgcn_readlane(__float_as_uint(v), l));
}

__device__ __forceinline__ ushort16 f32_to_bf16(float f) {
  uint32 u = __float_as_uint(f);
  u += 0x7FFF + ((u >> 16) & 1);          // round-to-nearest-even
  return (ushort16)(u >> 16);
}

// ==== PREP: blocks [0,pblocks) = ent_proj; blocks [pblocks,+16) = W2@cW fuse =
__global__ __launch_bounds__(256, 4) void kgat_prep(
    const float* __restrict__ ent_tab, const float* __restrict__ attn_W,
    float* __restrict__ proj, ushort16* __restrict__ ent_bf, int rows,
    int pblocks,
    const float* __restrict__ W2, const float* __restrict__ b2,
    const float* __restrict__ cW, const float* __restrict__ cb,
    float* __restrict__ W2cW, float* __restrict__ cb2)
{
  const int lane = threadIdx.x & 63;
  const int wv   = threadIdx.x >> 6;

  if ((int)blockIdx.x < pblocks) {
    const long wave = (long)blockIdx.x * 4 + wv;
    const long base = wave * GRP;
    if (base >= rows) return;
    const float Wn = attn_W[D + lane];
    float v[GRP];
#pragma unroll
    for (int i = 0; i < GRP; ++i) {
      long r = base + i; if (r > rows - 1) r = rows - 1;
      v[i] = ent_tab[r * D + lane];         // coalesced, contiguous rows
    }
    float s[GRP];
#pragma unroll
    for (int i = 0; i < GRP; ++i)
      s[i] = wave_sum64(v[i] * Wn);         // 10 independent butterfly chains
#pragma unroll
    for (int i = 0; i < GRP; ++i) {
      const long r = base + i;
      if (r < rows) ent_bf[r * D + lane] = f32_to_bf16(v[i]);
    }
    if (lane == 0) {
#pragma unroll
      for (int i = 0; i < GRP; ++i)
        if (base + i < rows) proj[base + i] = s[i];
    }
  } else {
    // weight fusion: W2cW = W2 @ cW_bot; cb2 = cb + b2 @ cW_bot
    const int d = ((int)blockIdx.x - pblocks) * 4 + wv;   // 0..63
    float acc = 0.f;
#pragma unroll 8
    for (int k = 0; k < D; ++k)
      acc = fmaf(W2[d * D + k], cW[(D + k) * D + lane], acc);
    W2cW[d * D + lane] = acc;
    if (d == 0) {
      float a2 = 0.f;
#pragma unroll 8
      for (int k = 0; k < D; ++k)
        a2 = fmaf(b2[k], cW[(D + k) * D + lane], a2);
      cb2[lane] = cb[lane] + a2;
    }
  }
}

// ===== A: attention (paired-row gathers) + h-GEMV hidden under gather stalls
#define PGRP 5

__device__ __forceinline__ void load_pair_grp(uint32 (&buf)[PGRP],
                                              const int* __restrict__ adjb,
                                              const uint32* __restrict__ ent32,
                                              int g, int half, int sub) {
#pragma unroll
  for (int i = 0; i < PGRP; ++i) {
    const int p = g * PGRP + i;
    int t0 = adjb[2 * p + 0]; t0 = t0 < 0 ? 0 : t0;
    int t1 = adjb[2 * p + 1]; t1 = t1 < 0 ? 0 : t1;
    const int t = half ? t1 : t0;
    buf[i] = ent32[(size_t)t * 32 + sub];   // 4B/lane, 2 rows per instruction
  }
}

__device__ __forceinline__ void acc_pair_grp(const uint32 (&buf)[PGRP],
                                             float e, int g, int half,
                                             float& lo0, float& lo1,
                                             float& hi0, float& hi1) {
#pragma unroll
  for (int i = 0; i < PGRP; ++i) {
    const int p = g * PGRP + i;
    const float w0 = readlane_f(e, 2 * p + 0);
    const float w1 = readlane_f(e, 2 * p + 1);
    const float w  = half ? w1 : w0;
    const float lo = __uint_as_float(buf[i] << 16);          // bf16 dim 2*sub
    const float hi = __uint_as_float(buf[i] & 0xFFFF0000u);  // bf16 dim 2*sub+1
    if (i & 1) { lo1 = fmaf(w, lo, lo1); hi1 = fmaf(w, hi, hi1); }
    else       { lo0 = fmaf(w, lo, lo0); hi0 = fmaf(w, hi, hi0); }
  }
}

__global__ __launch_bounds__(256, 4) void kgat_attn2h(
    const int* __restrict__ item_idx, const int* __restrict__ adj,
    const float* __restrict__ item_tab,
    const uint32* __restrict__ ent32, const float* __restrict__ proj,
    const float* __restrict__ attn_W, const float* __restrict__ attn_b,
    const float* __restrict__ W1, const float* __restrict__ b1,
    float* __restrict__ hws, int B)
{
  const int lane = threadIdx.x & 63;
  const int wv   = threadIdx.x >> 6;
  const int b    = blockIdx.x * 4 + wv;
  if (b >= B) return;
  const int half = lane >> 5;
  const int sub  = lane & 31;

  const int* adjb = adj + (long)b * NN;

  uint32 GA[PGRP], GB[PGRP];
  load_pair_grp(GA, adjb, ent32, 0, half, sub);
  load_pair_grp(GB, adjb, ent32, 1, half, sub);

  const float item = item_tab[(long)item_idx[b] * D + lane];
  const float base = wave_sum64(item * attn_W[lane]) + attn_b[0];  // uniform

  const int myn = lane < NN ? lane : NN - 1;
  int mi = adjb[myn]; mi = mi < 0 ? 0 : mi;
  float s = proj[mi] + base;
  s = s > 0.f ? s : 0.2f * s;                     // leaky_relu(0.2)
  // scores are leaky_relu of ~unit-variance dots, bounded well below 8 ->
  // exp(s-8) can't overflow, denom can't underflow to 0.
  const float e = (lane < NN) ? __expf(s - 8.0f) : 0.f;
  const float denom = wave_sum64(e);

  float lo0 = 0.f, lo1 = 0.f, hi0 = 0.f, hi1 = 0.f;
  acc_pair_grp(GA, e, 0, half, lo0, lo1, hi0, hi1);
  load_pair_grp(GA, adjb, ent32, 2, half, sub);
  acc_pair_grp(GB, e, 1, half, lo0, lo1, hi0, hi1);
  load_pair_grp(GB, adjb, ent32, 3, half, sub);
  acc_pair_grp(GA, e, 2, half, lo0, lo1, hi0, hi1);
  load_pair_grp(GA, adjb, ent32, 4, half, sub);
  acc_pair_grp(GB, e, 3, half, lo0, lo1, hi0, hi1);
  acc_pair_grp(GA, e, 4, half, lo0, lo1, hi0, hi1);

  // combine: after shfl_xor ALL lanes hold raw na dims {2*sub, 2*sub+1}
  float nlo = lo0 + lo1;
  float nhi = hi0 + hi1;
  nlo += __shfl_xor(nlo, 32, 64);
  nhi += __shfl_xor(nhi, 32, 64);
  const float inv = 1.0f / denom;

  // ---- h = relu(na @ W1 + b1), na = raw*inv (inv folded after the sum).
  //      64 readlane broadcasts + L1-hot W1 columns, hidden under gather
  //      stalls (attn is latency-bound, VALU ~30%, L1 idle).
  float h0 = 0.f, h1 = 0.f;
#pragma unroll
  for (int k = 0; k < D; k += 2) {
    const float a0 = readlane_f(nlo, k >> 1);    // raw na dim k   (even)
    const float a1 = readlane_f(nhi, k >> 1);    // raw na dim k+1 (odd)
    h0 = fmaf(a0, W1[(k + 0) * D + lane], h0);
    h1 = fmaf(a1, W1[(k + 1) * D + lane], h1);
  }
  const float h = fmaxf(fmaf(h0 + h1, inv, b1[lane]), 0.f);
  hws[(long)b * D + lane] = h;                   // coalesced 256B row
}

// ===== M: single-phase MLP, 4 elems/wave, no LDS ============================
// f = relu( item@cW_top + h@W2cW + cb2 ); score = dot([user,f], oW) + ob
__global__ __launch_bounds__(256, 4) void kgat_mlp2u(
    const int* __restrict__ user_idx, const int* __restrict__ item_idx,
    const float* __restrict__ user_tab, const float* __restrict__ item_tab,
    const float* __restrict__ hws,
    const float* __restrict__ cW,
    const float* __restrict__ W2cW, const float* __restrict__ cb2,
    const float* __restrict__ oW, const float* __restrict__ ob,
    float* __restrict__ out, int B)
{
  const int lane = threadIdx.x & 63;
  const int wv   = threadIdx.x >> 6;
  const int b0   = (blockIdx.x * 4 + wv) * 4;
  if (b0 >= B) return;

  const int bA = b0 + 0 < B ? b0 + 0 : B - 1;
  const int bB = b0 + 1 < B ? b0 + 1 : B - 1;
  const int bC = b0 + 2 < B ? b0 + 2 : B - 1;
  const int bD = b0 + 3 < B ? b0 + 3 : B - 1;

  // wave-uniform activation bases -> scalar-pipe float4 loads
  const int uA = __builtin_amdgcn_readfirstlane(bA);
  const int uB = __builtin_amdgcn_readfirstlane(bB);
  const int uC = __builtin_amdgcn_readfirstlane(bC);
  const int uD = __builtin_amdgcn_readfirstlane(bD);
  const float* hpA = hws + (long)uA * D;     // 4 consecutive rows: L2-hot
  const float* hpB = hws + (long)uB * D;
  const float* hpC = hws + (long)uC * D;
  const float* hpD = hws + (long)uD * D;
  const int iiA = __builtin_amdgcn_readfirstlane(item_idx[bA]);
  const int iiB = __builtin_amdgcn_readfirstlane(item_idx[bB]);
  const int iiC = __builtin_amdgcn_readfirstlane(item_idx[bC]);
  const int iiD = __builtin_amdgcn_readfirstlane(item_idx[bD]);
  const float* itpA = item_tab + (long)iiA * D;
  const float* itpB = item_tab + (long)iiB * D;
  const float* itpC = item_tab + (long)iiC * D;
  const float* itpD = item_tab + (long)iiD * D;

  // user rows per-lane (lane = dim), coalesced
  const float usA = user_tab[(long)user_idx[bA] * D + lane];
  const float usB = user_tab[(long)user_idx[bB] * D + lane];
  const float usC = user_tab[(long)user_idx[bC] * D + lane];
  const float usD = user_tab[(long)user_idx[bD] * D + lane];

  // ---- single merged loop: f += item@cW_top + h@W2cW (both scalar-fed) ----
  const float cb2v = cb2[lane];
  float fA0 = cb2v, fA1 = 0.f, fB0 = cb2v, fB1 = 0.f;
  float fC0 = cb2v, fC1 = 0.f, fD0 = cb2v, fD1 = 0.f;
#pragma unroll
  for (int d = 0; d < D; d += 4) {
    const float w0 = cW[(d + 0) * D + lane];
    const float w1 = cW[(d + 1) * D + lane];
    const float w2 = cW[(d + 2) * D + lane];
    const float w3 = cW[(d + 3) * D + lane];
    const float v0 = W2cW[(d + 0) * D + lane];
    const float v1 = W2cW[(d + 1) * D + lane];
    const float v2 = W2cW[(d + 2) * D + lane];
    const float v3 = W2cW[(d + 3) * D + lane];
    const float4 iA = *(const float4*)(itpA + d);
    const float4 iB = *(const float4*)(itpB + d);
    const float4 iC = *(const float4*)(itpC + d);
    const float4 iD = *(const float4*)(itpD + d);
    const float4 hA = *(const float4*)(hpA + d);
    const float4 hB = *(const float4*)(hpB + d);
    const float4 hC = *(const float4*)(hpC + d);
    const float4 hD = *(const float4*)(hpD + d);
    fA0 = fmaf(iA.x, w0, fA0); fA1 = fmaf(iA.y, w1, fA1);
    fA0 = fmaf(iA.z, w2, fA0); fA1 = fmaf(iA.w, w3, fA1);
    fA0 = fmaf(hA.x, v0, fA0); fA1 = fmaf(hA.y, v1, fA1);
    fA0 = fmaf(hA.z, v2, fA0); fA1 = fmaf(hA.w, v3, fA1);
    fB0 = fmaf(iB.x, w0, fB0); fB1 = fmaf(iB.y, w1, fB1);
    fB0 = fmaf(iB.z, w2, fB0); fB1 = fmaf(iB.w, w3, fB1);
    fB0 = fmaf(hB.x, v0, fB0); fB1 = fmaf(hB.y, v1, fB1);
    fB0 = fmaf(hB.z, v2, fB0); fB1 = fmaf(hB.w, v3, fB1);
    fC0 = fmaf(iC.x, w0, fC0); fC1 = fmaf(iC.y, w1, fC1);
    fC0 = fmaf(iC.z, w2, fC0); fC1 = fmaf(iC.w, w3, fC1);
    fC0 = fmaf(hC.x, v0, fC0); fC1 = fmaf(hC.y, v1, fC1);
    fC0 = fmaf(hC.z, v2, fC0); fC1 = fmaf(hC.w, v3, fC1);
    fD0 = fmaf(iD.x, w0, fD0); fD1 = fmaf(iD.y, w1, fD1);
    fD0 = fmaf(iD.z, w2, fD0); fD1 = fmaf(iD.w, w3, fD1);
    fD0 = fmaf(hD.x, v0, fD0); fD1 = fmaf(hD.y, v1, fD1);
    fD0 = fmaf(hD.z, v2, fD0); fD1 = fmaf(hD.w, v3, fD1);
  }
  const float fA = fmaxf(fA0 + fA1, 0.f);
  const float fB = fmaxf(fB0 + fB1, 0.f);
  const float fC = fmaxf(fC0 + fC1, 0.f);
  const float fD = fmaxf(fD0 + fD1, 0.f);

  // ---- score = dot([user, f], oW) + ob ----
  const float oWu = oW[lane];
  const float oWf = oW[D + lane];
  const float ob0 = ob[0];
  const float scA = wave_sum64(fmaf(usA, oWu, fA * oWf));
  const float scB = wave_sum64(fmaf(usB, oWu, fB * oWf));
  const float scC = wave_sum64(fmaf(usC, oWu, fC * oWf));
  const float scD = wave_sum64(fmaf(usD, oWu, fD * oWf));
  if (lane == 0) {
    out[bA] = scA + ob0;
    if (bB != bA) out[bB] = scB + ob0;
    if (bC != bB) out[bC] = scC + ob0;
    if (bD != bC) out[bD] = scD + ob0;
  }
}

// ================= fallback: exact R3 kernel (small/no workspace) ===========
__device__ __forceinline__ void load_grp(float (&buf)[GRP],
                                         const int* __restrict__ adjb,
                                         const float* __restrict__ ent_tab,
                                         int g, int lane) {
#pragma unroll
  for (int i = 0; i < GRP; ++i) {
    int t = adjb[g * GRP + i];
    t = t < 0 ? 0 : t;
    buf[i] = ent_tab[(long)t * D + lane];
  }
}

__device__ __forceinline__ void proc_grp(const float (&buf)[GRP],
                                         float Wn, float base,
                                         float& l0, float& l1, float& na) {
  float ex[GRP];
#pragma unroll
  for (int i = 0; i < GRP; ++i) {
    float t = wave_sum64(buf[i] * Wn) + base;
    t = t > 0.f ? t : 0.2f * t;
    ex[i] = __expf(t - 8.0f);
  }
#pragma unroll
  for (int i = 0; i < GRP; ++i) {
    if (i & 1) l1 += ex[i]; else l0 += ex[i];
    na = fmaf(ex[i], buf[i], na);
  }
}

__global__ __launch_bounds__(256, 4) void kgat_r3(
    const int* __restrict__ user_idx, const int* __restrict__ item_idx,
    const int* __restrict__ adj,
    const float* __restrict__ user_tab, const float* __restrict__ item_tab,
    const float* __restrict__ ent_tab,
    const float* __restrict__ attn_W, const float* __restrict__ attn_b,
    const float* __restrict__ W1, const float* __restrict__ b1,
    const float* __restrict__ W2, const float* __restrict__ b2,
    const float* __restrict__ cW, const float* __restrict__ cb,
    const float* __restrict__ oW, const float* __restrict__ ob,
    float* __restrict__ out, int B)
{
  const int lane = threadIdx.x & 63;
  const int wv   = threadIdx.x >> 6;
  const int b    = blockIdx.x * 4 + wv;
  if (b >= B) return;

  const float user = user_tab[(long)user_idx[b] * D + lane];
  const float oWu  = oW[lane];
  const float oWf  = oW[D + lane];
  const float item = item_tab[(long)item_idx[b] * D + lane];
  const float Wi   = attn_W[lane];
  const float Wn   = attn_W[D + lane];
  const float base = wave_sum64(item * Wi) + attn_b[0];
  const int* adjb = adj + b * NN;

  float na = 0.f, l0 = 0.f, l1 = 0.f;
  float A[GRP], Bv[GRP];
  load_grp(A,  adjb, ent_tab, 0, lane);
  load_grp(Bv, adjb, ent_tab, 1, lane);
  proc_grp(A,  Wn, base, l0, l1, na);
  load_grp(A,  adjb, ent_tab, 2, lane);
  proc_grp(Bv, Wn, base, l0, l1, na);
  load_grp(Bv, adjb, ent_tab, 3, lane);
  proc_grp(A,  Wn, base, l0, l1, na);
  load_grp(A,  adjb, ent_tab, 4, lane);
  proc_grp(Bv, Wn, base, l0, l1, na);
  proc_grp(A,  Wn, base, l0, l1, na);
  na /= (l0 + l1);

  float h0 = b1[lane], h1 = 0.f, h2 = 0.f, h3 = 0.f;
#pragma unroll
  for (int d = 0; d < D; d += 4) {
    h0 = fmaf(readlane_f(na, d + 0), W1[(d + 0) * D + lane], h0);
    h1 = fmaf(readlane_f(na, d + 1), W1[(d + 1) * D + lane], h1);
    h2 = fmaf(readlane_f(na, d + 2), W1[(d + 2) * D + lane], h2);
    h3 = fmaf(readlane_f(na, d + 3), W1[(d + 3) * D + lane], h3);
  }
  const float h = fmaxf((h0 + h1) + (h2 + h3), 0.f);

  float r0 = b2[lane], r1 = 0.f, r2 = 0.f, r3 = 0.f;
#pragma unroll
  for (int d = 0; d < D; d += 4) {
    r0 = fmaf(readlane_f(h, d + 0), W2[(d + 0) * D + lane], r0);
    r1 = fmaf(readlane_f(h, d + 1), W2[(d + 1) * D + lane], r1);
    r2 = fmaf(readlane_f(h, d + 2), W2[(d + 2) * D + lane], r2);
    r3 = fmaf(readlane_f(h, d + 3), W2[(d + 3) * D + lane], r3);
  }
  const float r = (r0 + r1) + (r2 + r3);

  float f0 = cb[lane], f1 = 0.f, f2 = 0.f, f3 = 0.f;
#pragma unroll
  for (int k = 0; k < D; k += 4) {
    f0 = fmaf(readlane_f(item, k + 0), cW[(k + 0) * D + lane], f0);
    f1 = fmaf(readlane_f(item, k + 1), cW[(k + 1) * D + lane], f1);
    f2 = fmaf(readlane_f(item, k + 2), cW[(k + 2) * D + lane], f2);
    f3 = fmaf(readlane_f(item, k + 3), cW[(k + 3) * D + lane], f3);
  }
#pragma unroll
  for (int k = 0; k < D; k += 4) {
    f0 = fmaf(readlane_f(r, k + 0), cW[(D + k + 0) * D + lane], f0);
    f1 = fmaf(readlane_f(r, k + 1), cW[(D + k + 1) * D + lane], f1);
    f2 = fmaf(readlane_f(r, k + 2), cW[(D + k + 2) * D + lane], f2);
    f3 = fmaf(readlane_f(r, k + 3), cW[(D + k + 3) * D + lane], f3);
  }
  const float f = fmaxf((f0 + f1) + (f2 + f3), 0.f);

  const float sc = wave_sum64(fmaf(user, oWu, f * oWf));
  if (lane == 0) out[b] = sc + ob[0];
}

extern "C" void kernel_launch(void* const* d_in, const int* in_sizes, int n_in,
                              void* d_out, int out_size, void* d_ws, size_t ws_size,
                              hipStream_t stream) {
  const int*   user_idx = (const int*)d_in[0];
  const int*   item_idx = (const int*)d_in[1];
  const int*   adj      = (const int*)d_in[2];
  const float* user_tab = (const float*)d_in[3];
  const float* item_tab = (const float*)d_in[4];
  const float* ent_tab  = (const float*)d_in[5];
  const float* attn_W   = (const float*)d_in[6];
  const float* attn_b   = (const float*)d_in[7];
  const float* W1       = (const float*)d_in[8];
  const float* b1       = (const float*)d_in[9];
  const float* W2       = (const float*)d_in[10];
  const float* b2       = (const float*)d_in[11];
  const float* cW       = (const float*)d_in[12];
  const float* cb       = (const float*)d_in[13];
  const float* oW       = (const float*)d_in[14];
  const float* ob       = (const float*)d_in[15];
  float* out = (float*)d_out;

  const int B    = in_sizes[0];
  const int rows = in_sizes[5] / D;               // entity count

  // ws layout: [proj f32][ent_bf bf16][hws f32][W2cW f32][cb2 f32]
  const size_t off_bf = ((size_t)rows * 4 + 255) & ~(size_t)255;
  const size_t off_h  = (off_bf + (size_t)rows * D * 2 + 255) & ~(size_t)255;
  const size_t off_w2 = (off_h + (size_t)B * D * 4 + 255) & ~(size_t)255;
  const size_t off_cb = off_w2 + (size_t)D * D * 4;
  const size_t need   = off_cb + (size_t)D * 4;

  if (ws_size >= need) {
    float*    proj   = (float*)d_ws;
    ushort16* ent_bf = (ushort16*)((char*)d_ws + off_bf);
    float*    hws    = (float*)((char*)d_ws + off_h);
    float*    W2cW   = (float*)((char*)d_ws + off_w2);
    float*    cb2    = (float*)((char*)d_ws + off_cb);
    const int waves   = (rows + GRP - 1) / GRP;
    const int pblocks = (waves + 3) / 4;
    const int ablocks = (B + 3) / 4;              // attention: 1 elem/wave
    const int mblocks = (B + 15) / 16;            // MLP: 4 elems/wave
    kgat_prep<<<pblocks + 16, 256, 0, stream>>>(ent_tab, attn_W, proj, ent_bf,
                                                rows, pblocks, W2, b2, cW, cb,
                                                W2cW, cb2);
    kgat_attn2h<<<ablocks, 256, 0, stream>>>(item_idx, adj, item_tab,
                                             (const uint32*)ent_bf, proj,
                                             attn_W, attn_b, W1, b1, hws, B);
    kgat_mlp2u<<<mblocks, 256, 0, stream>>>(user_idx, item_idx, user_tab,
                                            item_tab, hws, cW, W2cW, cb2,
                                            oW, ob, out, B);
  } else {
    const int blocks = (B + 3) / 4;
    kgat_r3<<<blocks, 256, 0, stream>>>(user_idx, item_idx, adj,
                                        user_tab, item_tab, ent_tab,
                                        attn_W, attn_b, W1, b1, W2, b2,
                                        cW, cb, oW, ob, out, B);
  }
}

// Round 25
// 51.837 us; speedup vs baseline: 1.2022x; 1.0967x over previous
//
#include <hip/hip_runtime.h>

#define NN 50
#define D 64
#define GRP 10

typedef unsigned int uint32;
typedef unsigned short ushort16;

__device__ __forceinline__ float wave_sum64(float x) {
#pragma unroll
  for (int off = 32; off > 0; off >>= 1)
    x += __shfl_xor(x, off, 64);
  return x;
}

__device__ __forceinline__ float readlane_f(float v, int l) {
  return __uint_as_float(__builtin_amdgcn_readlane(__float_as_uint(v), l));
}

__device__ __forceinline__ ushort16 f32_to_bf16(float f) {
  uint32 u = __float_as_uint(f);
  u += 0x7FFF + ((u >> 16) & 1);          // round-to-nearest-even
  return (ushort16)(u >> 16);
}

// ==== PREP: blocks [0,pblocks) = ent_proj; blocks [pblocks,+16) = W2@cW fuse =
__global__ __launch_bounds__(256, 4) void kgat_prep(
    const float* __restrict__ ent_tab, const float* __restrict__ attn_W,
    float* __restrict__ proj, ushort16* __restrict__ ent_bf, int rows,
    int pblocks,
    const float* __restrict__ W2, const float* __restrict__ b2,
    const float* __restrict__ cW, const float* __restrict__ cb,
    float* __restrict__ W2cW, float* __restrict__ cb2)
{
  const int lane = threadIdx.x & 63;
  const int wv   = threadIdx.x >> 6;

  if ((int)blockIdx.x < pblocks) {
    const long wave = (long)blockIdx.x * 4 + wv;
    const long base = wave * GRP;
    if (base >= rows) return;
    const float Wn = attn_W[D + lane];
    float v[GRP];
#pragma unroll
    for (int i = 0; i < GRP; ++i) {
      long r = base + i; if (r > rows - 1) r = rows - 1;
      v[i] = ent_tab[r * D + lane];         // coalesced, contiguous rows
    }
    float s[GRP];
#pragma unroll
    for (int i = 0; i < GRP; ++i)
      s[i] = wave_sum64(v[i] * Wn);         // 10 independent butterfly chains
#pragma unroll
    for (int i = 0; i < GRP; ++i) {
      const long r = base + i;
      if (r < rows) ent_bf[r * D + lane] = f32_to_bf16(v[i]);
    }
    if (lane == 0) {
#pragma unroll
      for (int i = 0; i < GRP; ++i)
        if (base + i < rows) proj[base + i] = s[i];
    }
  } else {
    // weight fusion: W2cW = W2 @ cW_bot; cb2 = cb + b2 @ cW_bot
    const int d = ((int)blockIdx.x - pblocks) * 4 + wv;   // 0..63
    float acc = 0.f;
#pragma unroll 8
    for (int k = 0; k < D; ++k)
      acc = fmaf(W2[d * D + k], cW[(D + k) * D + lane], acc);
    W2cW[d * D + lane] = acc;
    if (d == 0) {
      float a2 = 0.f;
#pragma unroll 8
      for (int k = 0; k < D; ++k)
        a2 = fmaf(b2[k], cW[(D + k) * D + lane], a2);
      cb2[lane] = cb[lane] + a2;
    }
  }
}

// ===== A: attention, paired-row gathers (R20-proven, 2 rows / wave-load) ====
#define PGRP 5

__device__ __forceinline__ void load_pair_grp(uint32 (&buf)[PGRP],
                                              const int* __restrict__ adjb,
                                              const uint32* __restrict__ ent32,
                                              int g, int half, int sub) {
#pragma unroll
  for (int i = 0; i < PGRP; ++i) {
    const int p = g * PGRP + i;
    int t0 = adjb[2 * p + 0]; t0 = t0 < 0 ? 0 : t0;
    int t1 = adjb[2 * p + 1]; t1 = t1 < 0 ? 0 : t1;
    const int t = half ? t1 : t0;
    buf[i] = ent32[(size_t)t * 32 + sub];   // 4B/lane, 2 rows per instruction
  }
}

__device__ __forceinline__ void acc_pair_grp(const uint32 (&buf)[PGRP],
                                             float e, int g, int half,
                                             float& lo0, float& lo1,
                                             float& hi0, float& hi1) {
#pragma unroll
  for (int i = 0; i < PGRP; ++i) {
    const int p = g * PGRP + i;
    const float w0 = readlane_f(e, 2 * p + 0);
    const float w1 = readlane_f(e, 2 * p + 1);
    const float w  = half ? w1 : w0;
    const float lo = __uint_as_float(buf[i] << 16);          // bf16 dim 2*sub
    const float hi = __uint_as_float(buf[i] & 0xFFFF0000u);  // bf16 dim 2*sub+1
    if (i & 1) { lo1 = fmaf(w, lo, lo1); hi1 = fmaf(w, hi, hi1); }
    else       { lo0 = fmaf(w, lo, lo0); hi0 = fmaf(w, hi, hi0); }
  }
}

__global__ __launch_bounds__(256, 4) void kgat_attn2(
    const int* __restrict__ item_idx, const int* __restrict__ adj,
    const float* __restrict__ item_tab,
    const uint32* __restrict__ ent32, const float* __restrict__ proj,
    const float* __restrict__ attn_W, const float* __restrict__ attn_b,
    float* __restrict__ naws, int B)
{
  const int lane = threadIdx.x & 63;
  const int wv   = threadIdx.x >> 6;
  const int b    = blockIdx.x * 4 + wv;
  if (b >= B) return;
  const int half = lane >> 5;
  const int sub  = lane & 31;

  const int* adjb = adj + (long)b * NN;

  uint32 GA[PGRP], GB[PGRP];
  load_pair_grp(GA, adjb, ent32, 0, half, sub);
  load_pair_grp(GB, adjb, ent32, 1, half, sub);

  const float item = item_tab[(long)item_idx[b] * D + lane];
  const float base = wave_sum64(item * attn_W[lane]) + attn_b[0];  // uniform

  const int myn = lane < NN ? lane : NN - 1;
  int mi = adjb[myn]; mi = mi < 0 ? 0 : mi;
  float s = proj[mi] + base;
  s = s > 0.f ? s : 0.2f * s;                     // leaky_relu(0.2)
  // scores are leaky_relu of ~unit-variance dots, bounded well below 8 ->
  // exp(s-8) can't overflow, denom can't underflow to 0.
  const float e = (lane < NN) ? __expf(s - 8.0f) : 0.f;
  const float denom = wave_sum64(e);

  float lo0 = 0.f, lo1 = 0.f, hi0 = 0.f, hi1 = 0.f;
  acc_pair_grp(GA, e, 0, half, lo0, lo1, hi0, hi1);
  load_pair_grp(GA, adjb, ent32, 2, half, sub);
  acc_pair_grp(GB, e, 1, half, lo0, lo1, hi0, hi1);
  load_pair_grp(GB, adjb, ent32, 3, half, sub);
  acc_pair_grp(GA, e, 2, half, lo0, lo1, hi0, hi1);
  load_pair_grp(GA, adjb, ent32, 4, half, sub);
  acc_pair_grp(GB, e, 3, half, lo0, lo1, hi0, hi1);
  acc_pair_grp(GA, e, 4, half, lo0, lo1, hi0, hi1);

  float nlo = lo0 + lo1;
  float nhi = hi0 + hi1;
  nlo += __shfl_xor(nlo, 32, 64);
  nhi += __shfl_xor(nhi, 32, 64);

  const float inv = 1.0f / denom;
  if (lane < 32) {                                 // coalesced float2 store
    float2 val = make_float2(nlo * inv, nhi * inv);
    *(float2*)(naws + (long)b * D + 2 * sub) = val;
  }
}

// ===== M: fused MLP; phase A merges na@W1 with item@cW (independent) ========
// f = relu( item@cW_top + h@W2cW + cb2 ), h = relu(na@W1 + b1)
__global__ __launch_bounds__(256, 4) void kgat_mlpf(
    const int* __restrict__ user_idx, const int* __restrict__ item_idx,
    const float* __restrict__ user_tab, const float* __restrict__ item_tab,
    const float* __restrict__ naws,
    const float* __restrict__ W1, const float* __restrict__ b1,
    const float* __restrict__ cW,
    const float* __restrict__ W2cW, const float* __restrict__ cb2,
    const float* __restrict__ oW, const float* __restrict__ ob,
    float* __restrict__ out, int B)
{
  __shared__ __align__(16) float s_h[4 * 4 * D];   // h broadcast (4 elem/wave)

  const int lane = threadIdx.x & 63;
  const int wv   = threadIdx.x >> 6;
  const int b0   = (blockIdx.x * 4 + wv) * 4;
  if (b0 >= B) return;

  float* shA = s_h + (wv * 4 + 0) * D;
  float* shB = s_h + (wv * 4 + 1) * D;
  float* shC = s_h + (wv * 4 + 2) * D;
  float* shD = s_h + (wv * 4 + 3) * D;

  const int bA = b0 + 0 < B ? b0 + 0 : B - 1;
  const int bB = b0 + 1 < B ? b0 + 1 : B - 1;
  const int bC = b0 + 2 < B ? b0 + 2 : B - 1;
  const int bD = b0 + 3 < B ? b0 + 3 : B - 1;

  // wave-uniform activation bases -> scalar-pipe loads (s_load_dwordx4)
  const int uA = __builtin_amdgcn_readfirstlane(bA);
  const int uB = __builtin_amdgcn_readfirstlane(bB);
  const int uC = __builtin_amdgcn_readfirstlane(bC);
  const int uD = __builtin_amdgcn_readfirstlane(bD);
  const float* napA = naws + (long)uA * D;
  const float* napB = naws + (long)uB * D;
  const float* napC = naws + (long)uC * D;
  const float* napD = naws + (long)uD * D;
  const int iiA = __builtin_amdgcn_readfirstlane(item_idx[bA]);
  const int iiB = __builtin_amdgcn_readfirstlane(item_idx[bB]);
  const int iiC = __builtin_amdgcn_readfirstlane(item_idx[bC]);
  const int iiD = __builtin_amdgcn_readfirstlane(item_idx[bD]);
  const float* itpA = item_tab + (long)iiA * D;
  const float* itpB = item_tab + (long)iiB * D;
  const float* itpC = item_tab + (long)iiC * D;
  const float* itpD = item_tab + (long)iiD * D;

  // user rows per-lane (lane = dim), coalesced
  const float usA = user_tab[(long)user_idx[bA] * D + lane];
  const float usB = user_tab[(long)user_idx[bB] * D + lane];
  const float usC = user_tab[(long)user_idx[bC] * D + lane];
  const float usD = user_tab[(long)user_idx[bD] * D + lane];

  // ---- phase A (merged): h-acc = na@W1 + b1  AND  f-acc = item@cW + cb2 ----
  const float b1v  = b1[lane];
  const float cb2v = cb2[lane];
  float hA0 = b1v, hA1 = 0.f, hB0 = b1v, hB1 = 0.f;
  float hC0 = b1v, hC1 = 0.f, hD0 = b1v, hD1 = 0.f;
  float fA0 = cb2v, fA1 = 0.f, fB0 = cb2v, fB1 = 0.f;
  float fC0 = cb2v, fC1 = 0.f, fD0 = cb2v, fD1 = 0.f;
#pragma unroll
  for (int d = 0; d < D; d += 4) {
    const float v0 = W1[(d + 0) * D + lane];
    const float v1 = W1[(d + 1) * D + lane];
    const float v2 = W1[(d + 2) * D + lane];
    const float v3 = W1[(d + 3) * D + lane];
    const float w0 = cW[(d + 0) * D + lane];
    const float w1 = cW[(d + 1) * D + lane];
    const float w2 = cW[(d + 2) * D + lane];
    const float w3 = cW[(d + 3) * D + lane];
    const float4 aA = *(const float4*)(napA + d);
    const float4 aB = *(const float4*)(napB + d);
    const float4 aC = *(const float4*)(napC + d);
    const float4 aD = *(const float4*)(napD + d);
    const float4 iA = *(const float4*)(itpA + d);
    const float4 iB = *(const float4*)(itpB + d);
    const float4 iC = *(const float4*)(itpC + d);
    const float4 iD = *(const float4*)(itpD + d);
    hA0 = fmaf(aA.x, v0, hA0); hA1 = fmaf(aA.y, v1, hA1);
    hA0 = fmaf(aA.z, v2, hA0); hA1 = fmaf(aA.w, v3, hA1);
    hB0 = fmaf(aB.x, v0, hB0); hB1 = fmaf(aB.y, v1, hB1);
    hB0 = fmaf(aB.z, v2, hB0); hB1 = fmaf(aB.w, v3, hB1);
    hC0 = fmaf(aC.x, v0, hC0); hC1 = fmaf(aC.y, v1, hC1);
    hC0 = fmaf(aC.z, v2, hC0); hC1 = fmaf(aC.w, v3, hC1);
    hD0 = fmaf(aD.x, v0, hD0); hD1 = fmaf(aD.y, v1, hD1);
    hD0 = fmaf(aD.z, v2, hD0); hD1 = fmaf(aD.w, v3, hD1);
    fA0 = fmaf(iA.x, w0, fA0); fA1 = fmaf(iA.y, w1, fA1);
    fA0 = fmaf(iA.z, w2, fA0); fA1 = fmaf(iA.w, w3, fA1);
    fB0 = fmaf(iB.x, w0, fB0); fB1 = fmaf(iB.y, w1, fB1);
    fB0 = fmaf(iB.z, w2, fB0); fB1 = fmaf(iB.w, w3, fB1);
    fC0 = fmaf(iC.x, w0, fC0); fC1 = fmaf(iC.y, w1, fC1);
    fC0 = fmaf(iC.z, w2, fC0); fC1 = fmaf(iC.w, w3, fC1);
    fD0 = fmaf(iD.x, w0, fD0); fD1 = fmaf(iD.y, w1, fD1);
    fD0 = fmaf(iD.z, w2, fD0); fD1 = fmaf(iD.w, w3, fD1);
  }
  shA[lane] = fmaxf(hA0 + hA1, 0.f);               // wave-private, no barrier
  shB[lane] = fmaxf(hB0 + hB1, 0.f);
  shC[lane] = fmaxf(hC0 + hC1, 0.f);
  shD[lane] = fmaxf(hD0 + hD1, 0.f);

  // ---- phase B: f += h @ W2cW (h via LDS broadcast) ----
#pragma unroll
  for (int d = 0; d < D; d += 4) {
    const float w0 = W2cW[(d + 0) * D + lane];
    const float w1 = W2cW[(d + 1) * D + lane];
    const float w2 = W2cW[(d + 2) * D + lane];
    const float w3 = W2cW[(d + 3) * D + lane];
    const float4 cA = *(const float4*)(shA + d);
    const float4 cB = *(const float4*)(shB + d);
    const float4 cC = *(const float4*)(shC + d);
    const float4 cD = *(const float4*)(shD + d);
    fA0 = fmaf(cA.x, w0, fA0); fA1 = fmaf(cA.y, w1, fA1);
    fA0 = fmaf(cA.z, w2, fA0); fA1 = fmaf(cA.w, w3, fA1);
    fB0 = fmaf(cB.x, w0, fB0); fB1 = fmaf(cB.y, w1, fB1);
    fB0 = fmaf(cB.z, w2, fB0); fB1 = fmaf(cB.w, w3, fB1);
    fC0 = fmaf(cC.x, w0, fC0); fC1 = fmaf(cC.y, w1, fC1);
    fC0 = fmaf(cC.z, w2, fC0); fC1 = fmaf(cC.w, w3, fC1);
    fD0 = fmaf(cD.x, w0, fD0); fD1 = fmaf(cD.y, w1, fD1);
    fD0 = fmaf(cD.z, w2, fD0); fD1 = fmaf(cD.w, w3, fD1);
  }
  const float fA = fmaxf(fA0 + fA1, 0.f);
  const float fB = fmaxf(fB0 + fB1, 0.f);
  const float fC = fmaxf(fC0 + fC1, 0.f);
  const float fD = fmaxf(fD0 + fD1, 0.f);

  // ---- score = dot([user, f], oW) + ob ----
  const float oWu = oW[lane];
  const float oWf = oW[D + lane];
  const float ob0 = ob[0];
  const float scA = wave_sum64(fmaf(usA, oWu, fA * oWf));
  const float scB = wave_sum64(fmaf(usB, oWu, fB * oWf));
  const float scC = wave_sum64(fmaf(usC, oWu, fC * oWf));
  const float scD = wave_sum64(fmaf(usD, oWu, fD * oWf));
  if (lane == 0) {
    out[bA] = scA + ob0;
    if (bB != bA) out[bB] = scB + ob0;
    if (bC != bB) out[bC] = scC + ob0;
    if (bD != bC) out[bD] = scD + ob0;
  }
}

// ================= fallback: exact R3 kernel (small/no workspace) ===========
__device__ __forceinline__ void load_grp(float (&buf)[GRP],
                                         const int* __restrict__ adjb,
                                         const float* __restrict__ ent_tab,
                                         int g, int lane) {
#pragma unroll
  for (int i = 0; i < GRP; ++i) {
    int t = adjb[g * GRP + i];
    t = t < 0 ? 0 : t;
    buf[i] = ent_tab[(long)t * D + lane];
  }
}

__device__ __forceinline__ void proc_grp(const float (&buf)[GRP],
                                         float Wn, float base,
                                         float& l0, float& l1, float& na) {
  float ex[GRP];
#pragma unroll
  for (int i = 0; i < GRP; ++i) {
    float t = wave_sum64(buf[i] * Wn) + base;
    t = t > 0.f ? t : 0.2f * t;
    ex[i] = __expf(t - 8.0f);
  }
#pragma unroll
  for (int i = 0; i < GRP; ++i) {
    if (i & 1) l1 += ex[i]; else l0 += ex[i];
    na = fmaf(ex[i], buf[i], na);
  }
}

__global__ __launch_bounds__(256, 4) void kgat_r3(
    const int* __restrict__ user_idx, const int* __restrict__ item_idx,
    const int* __restrict__ adj,
    const float* __restrict__ user_tab, const float* __restrict__ item_tab,
    const float* __restrict__ ent_tab,
    const float* __restrict__ attn_W, const float* __restrict__ attn_b,
    const float* __restrict__ W1, const float* __restrict__ b1,
    const float* __restrict__ W2, const float* __restrict__ b2,
    const float* __restrict__ cW, const float* __restrict__ cb,
    const float* __restrict__ oW, const float* __restrict__ ob,
    float* __restrict__ out, int B)
{
  const int lane = threadIdx.x & 63;
  const int wv   = threadIdx.x >> 6;
  const int b    = blockIdx.x * 4 + wv;
  if (b >= B) return;

  const float user = user_tab[(long)user_idx[b] * D + lane];
  const float oWu  = oW[lane];
  const float oWf  = oW[D + lane];
  const float item = item_tab[(long)item_idx[b] * D + lane];
  const float Wi   = attn_W[lane];
  const float Wn   = attn_W[D + lane];
  const float base = wave_sum64(item * Wi) + attn_b[0];
  const int* adjb = adj + b * NN;

  float na = 0.f, l0 = 0.f, l1 = 0.f;
  float A[GRP], Bv[GRP];
  load_grp(A,  adjb, ent_tab, 0, lane);
  load_grp(Bv, adjb, ent_tab, 1, lane);
  proc_grp(A,  Wn, base, l0, l1, na);
  load_grp(A,  adjb, ent_tab, 2, lane);
  proc_grp(Bv, Wn, base, l0, l1, na);
  load_grp(Bv, adjb, ent_tab, 3, lane);
  proc_grp(A,  Wn, base, l0, l1, na);
  load_grp(A,  adjb, ent_tab, 4, lane);
  proc_grp(Bv, Wn, base, l0, l1, na);
  proc_grp(A,  Wn, base, l0, l1, na);
  na /= (l0 + l1);

  float h0 = b1[lane], h1 = 0.f, h2 = 0.f, h3 = 0.f;
#pragma unroll
  for (int d = 0; d < D; d += 4) {
    h0 = fmaf(readlane_f(na, d + 0), W1[(d + 0) * D + lane], h0);
    h1 = fmaf(readlane_f(na, d + 1), W1[(d + 1) * D + lane], h1);
    h2 = fmaf(readlane_f(na, d + 2), W1[(d + 2) * D + lane], h2);
    h3 = fmaf(readlane_f(na, d + 3), W1[(d + 3) * D + lane], h3);
  }
  const float h = fmaxf((h0 + h1) + (h2 + h3), 0.f);

  float r0 = b2[lane], r1 = 0.f, r2 = 0.f, r3 = 0.f;
#pragma unroll
  for (int d = 0; d < D; d += 4) {
    r0 = fmaf(readlane_f(h, d + 0), W2[(d + 0) * D + lane], r0);
    r1 = fmaf(readlane_f(h, d + 1), W2[(d + 1) * D + lane], r1);
    r2 = fmaf(readlane_f(h, d + 2), W2[(d + 2) * D + lane], r2);
    r3 = fmaf(readlane_f(h, d + 3), W2[(d + 3) * D + lane], r3);
  }
  const float r = (r0 + r1) + (r2 + r3);

  float f0 = cb[lane], f1 = 0.f, f2 = 0.f, f3 = 0.f;
#pragma unroll
  for (int k = 0; k < D; k += 4) {
    f0 = fmaf(readlane_f(item, k + 0), cW[(k + 0) * D + lane], f0);
    f1 = fmaf(readlane_f(item, k + 1), cW[(k + 1) * D + lane], f1);
    f2 = fmaf(readlane_f(item, k + 2), cW[(k + 2) * D + lane], f2);
    f3 = fmaf(readlane_f(item, k + 3), cW[(k + 3) * D + lane], f3);
  }
#pragma unroll
  for (int k = 0; k < D; k += 4) {
    f0 = fmaf(readlane_f(r, k + 0), cW[(D + k + 0) * D + lane], f0);
    f1 = fmaf(readlane_f(r, k + 1), cW[(D + k + 1) * D + lane], f1);
    f2 = fmaf(readlane_f(r, k + 2), cW[(D + k + 2) * D + lane], f2);
    f3 = fmaf(readlane_f(r, k + 3), cW[(D + k + 3) * D + lane], f3);
  }
  const float f = fmaxf((f0 + f1) + (f2 + f3), 0.f);

  const float sc = wave_sum64(fmaf(user, oWu, f * oWf));
  if (lane == 0) out[b] = sc + ob[0];
}

extern "C" void kernel_launch(void* const* d_in, const int* in_sizes, int n_in,
                              void* d_out, int out_size, void* d_ws, size_t ws_size,
                              hipStream_t stream) {
  const int*   user_idx = (const int*)d_in[0];
  const int*   item_idx = (const int*)d_in[1];
  const int*   adj      = (const int*)d_in[2];
  const float* user_tab = (const float*)d_in[3];
  const float* item_tab = (const float*)d_in[4];
  const float* ent_tab  = (const float*)d_in[5];
  const float* attn_W   = (const float*)d_in[6];
  const float* attn_b   = (const float*)d_in[7];
  const float* W1       = (const float*)d_in[8];
  const float* b1       = (const float*)d_in[9];
  const float* W2       = (const float*)d_in[10];
  const float* b2       = (const float*)d_in[11];
  const float* cW       = (const float*)d_in[12];
  const float* cb       = (const float*)d_in[13];
  const float* oW       = (const float*)d_in[14];
  const float* ob       = (const float*)d_in[15];
  float* out = (float*)d_out;

  const int B    = in_sizes[0];
  const int rows = in_sizes[5] / D;               // entity count

  // ws layout: [proj f32][ent_bf bf16][naws f32][W2cW f32][cb2 f32]
  const size_t off_bf = ((size_t)rows * 4 + 255) & ~(size_t)255;
  const size_t off_na = (off_bf + (size_t)rows * D * 2 + 255) & ~(size_t)255;
  const size_t off_w2 = (off_na + (size_t)B * D * 4 + 255) & ~(size_t)255;
  const size_t off_cb = off_w2 + (size_t)D * D * 4;
  const size_t need   = off_cb + (size_t)D * 4;

  if (ws_size >= need) {
    float*    proj   = (float*)d_ws;
    ushort16* ent_bf = (ushort16*)((char*)d_ws + off_bf);
    float*    naws   = (float*)((char*)d_ws + off_na);
    float*    W2cW   = (float*)((char*)d_ws + off_w2);
    float*    cb2    = (float*)((char*)d_ws + off_cb);
    const int waves   = (rows + GRP - 1) / GRP;
    const int pblocks = (waves + 3) / 4;
    const int ablocks = (B + 3) / 4;              // attention: 1 elem/wave
    const int mblocks = (B + 15) / 16;            // MLP: 4 elems/wave
    kgat_prep<<<pblocks + 16, 256, 0, stream>>>(ent_tab, attn_W, proj, ent_bf,
                                                rows, pblocks, W2, b2, cW, cb,
                                                W2cW, cb2);
    kgat_attn2<<<ablocks, 256, 0, stream>>>(item_idx, adj, item_tab,
                                            (const uint32*)ent_bf, proj,
                                            attn_W, attn_b, naws, B);
    kgat_mlpf<<<mblocks, 256, 0, stream>>>(user_idx, item_idx, user_tab,
                                           item_tab, naws, W1, b1, cW,
                                           W2cW, cb2, oW, ob, out, B);
  } else {
    const int blocks = (B + 3) / 4;
    kgat_r3<<<blocks, 256, 0, stream>>>(user_idx, item_idx, adj,
                                        user_tab, item_tab, ent_tab,
                                        attn_W, attn_b, W1, b1, W2, b2,
                                        cW, cb, oW, ob, out, B);
  }
}